// Round 1
// baseline (347.219 us; speedup 1.0000x reference)
//
#include <hip/hip_runtime.h>
#include <math.h>

// y[b,t,d] = Re(z[t]),  z[t] = r*z[t-1] + x[t],  r = exp(-|decay[d]|) * e^{i*freq[d]}
//
// 3-kernel blocked scan over t, C chunks of length L = T/C:
//   carry : per chunk, end-state from zero init (reads x once). Chain is stepped
//           once per 4 timesteps using r^4 (precomputed r^1..r^4), so the serial
//           dependence is 2 FMAs per 4 t's instead of per 1 t.
//   scan  : tiny O(C) exclusive prefix scan over zloc (replaces the old O(C^2)
//           per-block Horner -> removes 268 MB of L2 traffic + 127-deep serial
//           loops from the final pass, and lets C grow to 256 for occupancy).
//   final : per chunk, start from scanned-in state, recompute chunk emitting y.
//           Intermediate outputs y[t..t+2] are computed OFF the chain (real
//           parts only); only z[t+3] feeds back.

#define D_DIM 1024

typedef float floatx4 __attribute__((ext_vector_type(4)));

struct RPow {
  float cr1[4], ci1[4];
  float cr2[4], ci2[4];
  float cr3[4], ci3[4];
  float cr4[4], ci4[4];
};

__device__ __forceinline__ void load_rpow(const float* __restrict__ decay,
                                          const float* __restrict__ freq, int d,
                                          RPow& P) {
  float4 dv = *(const float4*)(decay + d);
  float4 fv = *(const float4*)(freq + d);
  float a[4] = {dv.x, dv.y, dv.z, dv.w};
  float w[4] = {fv.x, fv.y, fv.z, fv.w};
#pragma unroll
  for (int k = 0; k < 4; ++k) {
    float ak = fabsf(a[k]);
    float e = expf(-ak);
    float rr = e * cosf(w[k]);
    float ri = e * sinf(w[k]);
    P.cr1[k] = rr;
    P.ci1[k] = ri;
    float r2r = fmaf(rr, rr, -ri * ri);
    float r2i = 2.f * rr * ri;
    P.cr2[k] = r2r;
    P.ci2[k] = r2i;
    P.cr3[k] = fmaf(r2r, rr, -r2i * ri);
    P.ci3[k] = fmaf(r2r, ri, r2i * rr);
    P.cr4[k] = fmaf(r2r, r2r, -r2i * r2i);
    P.ci4[k] = 2.f * r2r * r2i;
  }
}

__global__ __launch_bounds__(256, 4) void carry_kernel(
    const float* __restrict__ x, const float* __restrict__ decay,
    const float* __restrict__ freq, float2* __restrict__ zloc,
    int T, int L, int C) {
  const int c = blockIdx.x;
  const int b = blockIdx.y;
  const int d = threadIdx.x * 4;  // 4 channels/thread; block covers D=1024

  RPow P;
  load_rpow(decay, freq, d, P);

  const float4* xp =
      (const float4*)(x + ((size_t)b * T + (size_t)c * L) * D_DIM + d);
  const size_t stride = D_DIM / 4;

  float zr[4] = {0.f, 0.f, 0.f, 0.f}, zi[4] = {0.f, 0.f, 0.f, 0.f};
  const int G = L >> 2;  // L is always a multiple of 4 (T=8192, C pow2 <= 2048)
#pragma unroll 2
  for (int g = 0; g < G; ++g) {
    const float4* xg = xp + (size_t)g * 4 * stride;
    float4 v0 = xg[0];
    float4 v1 = xg[stride];
    float4 v2 = xg[2 * stride];
    float4 v3 = xg[3 * stride];
    float X0[4] = {v0.x, v0.y, v0.z, v0.w};
    float X1[4] = {v1.x, v1.y, v1.z, v1.w};
    float X2[4] = {v2.x, v2.y, v2.z, v2.w};
    float X3[4] = {v3.x, v3.y, v3.z, v3.w};
#pragma unroll
    for (int k = 0; k < 4; ++k) {
      // x-only horizontal part (independent of state)
      float sr = fmaf(P.cr3[k], X0[k], fmaf(P.cr2[k], X1[k], fmaf(P.cr1[k], X2[k], X3[k])));
      float si = fmaf(P.ci3[k], X0[k], fmaf(P.ci2[k], X1[k], P.ci1[k] * X2[k]));
      // chain: z' = r^4 * z + s   (only 2 dependent FMAs per 4 timesteps)
      float nr = fmaf(P.cr4[k], zr[k], fmaf(-P.ci4[k], zi[k], sr));
      float ni = fmaf(P.cr4[k], zi[k], fmaf(P.ci4[k], zr[k], si));
      zr[k] = nr;
      zi[k] = ni;
    }
  }

  float4* zp = (float4*)(zloc + ((size_t)b * C + c) * D_DIM + d);
  zp[0] = make_float4(zr[0], zi[0], zr[1], zi[1]);
  zp[1] = make_float4(zr[2], zi[2], zr[3], zi[3]);
}

// Exclusive prefix scan over chunk carries: zloc[c] <- sum_{j<c} r^{L(c-1-j)} zloc[j].
// Grid = (B); 4 blocks, serial over C (tiny: ~C iterations of L2-resident work).
__global__ __launch_bounds__(256) void scan_kernel(
    const float* __restrict__ decay, const float* __restrict__ freq,
    float2* __restrict__ zloc, int L, int C) {
  const int b = blockIdx.x;
  const int d = threadIdx.x * 4;

  float4 dv = *(const float4*)(decay + d);
  float4 fv = *(const float4*)(freq + d);
  float a[4] = {dv.x, dv.y, dv.z, dv.w};
  float w[4] = {fv.x, fv.y, fv.z, fv.w};
  float rLr[4], rLi[4];
  const float fL = (float)L;
#pragma unroll
  for (int k = 0; k < 4; ++k) {
    float e = expf(-fabsf(a[k]) * fL);
    rLr[k] = e * cosf(w[k] * fL);
    rLi[k] = e * sinf(w[k] * fL);
  }

  float2* zl = zloc + (size_t)b * C * D_DIM + d;
  float Zr[4] = {0.f, 0.f, 0.f, 0.f}, Zi[4] = {0.f, 0.f, 0.f, 0.f};
  for (int j = 0; j < C - 1; ++j) {
    float4 v0 = *(const float4*)(zl + (size_t)j * D_DIM);
    float4 v1 = *(const float4*)(zl + (size_t)j * D_DIM + 2);
    // store exclusive prefix (state entering chunk j)
    *(float4*)(zl + (size_t)j * D_DIM) = make_float4(Zr[0], Zi[0], Zr[1], Zi[1]);
    *(float4*)(zl + (size_t)j * D_DIM + 2) = make_float4(Zr[2], Zi[2], Zr[3], Zi[3]);
    float lr[4] = {v0.x, v0.z, v1.x, v1.z};
    float li[4] = {v0.y, v0.w, v1.y, v1.w};
#pragma unroll
    for (int k = 0; k < 4; ++k) {
      float nr = fmaf(rLr[k], Zr[k], fmaf(-rLi[k], Zi[k], lr[k]));
      float ni = fmaf(rLr[k], Zi[k], fmaf(rLi[k], Zr[k], li[k]));
      Zr[k] = nr;
      Zi[k] = ni;
    }
  }
  *(float4*)(zl + (size_t)(C - 1) * D_DIM) = make_float4(Zr[0], Zi[0], Zr[1], Zi[1]);
  *(float4*)(zl + (size_t)(C - 1) * D_DIM + 2) = make_float4(Zr[2], Zi[2], Zr[3], Zi[3]);
}

__global__ __launch_bounds__(256, 4) void final_kernel(
    const float* __restrict__ x, const float* __restrict__ decay,
    const float* __restrict__ freq, const float2* __restrict__ zloc,
    float* __restrict__ y, int T, int L, int C) {
  const int c = blockIdx.x;
  const int b = blockIdx.y;
  const int d = threadIdx.x * 4;

  RPow P;
  load_rpow(decay, freq, d, P);

  // incoming state (scanned)
  const float2* zl = zloc + ((size_t)b * C + c) * D_DIM + d;
  float4 z0 = *(const float4*)(zl);
  float4 z1 = *(const float4*)(zl + 2);
  float zr[4] = {z0.x, z0.z, z1.x, z1.z};
  float zi[4] = {z0.y, z0.w, z1.y, z1.w};

  const size_t off = ((size_t)b * T + (size_t)c * L) * D_DIM + d;
  const float4* xp = (const float4*)(x + off);
  floatx4* yp = (floatx4*)(y + off);
  const size_t stride = D_DIM / 4;

  const int G = L >> 2;
#pragma unroll 2
  for (int g = 0; g < G; ++g) {
    const float4* xg = xp + (size_t)g * 4 * stride;
    float4 v0 = xg[0];
    float4 v1 = xg[stride];
    float4 v2 = xg[2 * stride];
    float4 v3 = xg[3 * stride];
    float X0[4] = {v0.x, v0.y, v0.z, v0.w};
    float X1[4] = {v1.x, v1.y, v1.z, v1.w};
    float X2[4] = {v2.x, v2.y, v2.z, v2.w};
    float X3[4] = {v3.x, v3.y, v3.z, v3.w};
    float Y0[4], Y1[4], Y2[4], Y3[4];
#pragma unroll
    for (int k = 0; k < 4; ++k) {
      // off-chain real-part outputs for t, t+1, t+2
      Y0[k] = fmaf(P.cr1[k], zr[k], fmaf(-P.ci1[k], zi[k], X0[k]));
      Y1[k] = fmaf(P.cr2[k], zr[k],
                   fmaf(-P.ci2[k], zi[k], fmaf(P.cr1[k], X0[k], X1[k])));
      Y2[k] = fmaf(P.cr3[k], zr[k],
                   fmaf(-P.ci3[k], zi[k],
                        fmaf(P.cr2[k], X0[k], fmaf(P.cr1[k], X1[k], X2[k]))));
      // chain step: z' = r^4 * z + s
      float sr = fmaf(P.cr3[k], X0[k], fmaf(P.cr2[k], X1[k], fmaf(P.cr1[k], X2[k], X3[k])));
      float si = fmaf(P.ci3[k], X0[k], fmaf(P.ci2[k], X1[k], P.ci1[k] * X2[k]));
      float nr = fmaf(P.cr4[k], zr[k], fmaf(-P.ci4[k], zi[k], sr));
      float ni = fmaf(P.cr4[k], zi[k], fmaf(P.ci4[k], zr[k], si));
      zr[k] = nr;
      zi[k] = ni;
      Y3[k] = nr;  // Re(z[t+3])
    }
    // Non-temporal: y is never re-read; keep x L3-resident instead.
    floatx4 o0 = {Y0[0], Y0[1], Y0[2], Y0[3]};
    floatx4 o1 = {Y1[0], Y1[1], Y1[2], Y1[3]};
    floatx4 o2 = {Y2[0], Y2[1], Y2[2], Y2[3]};
    floatx4 o3 = {Y3[0], Y3[1], Y3[2], Y3[3]};
    floatx4* yg = yp + (size_t)g * 4 * stride;
    __builtin_nontemporal_store(o0, &yg[0]);
    __builtin_nontemporal_store(o1, &yg[stride]);
    __builtin_nontemporal_store(o2, &yg[2 * stride]);
    __builtin_nontemporal_store(o3, &yg[3 * stride]);
  }
}

extern "C" void kernel_launch(void* const* d_in, const int* in_sizes, int n_in,
                              void* d_out, int out_size, void* d_ws, size_t ws_size,
                              hipStream_t stream) {
  const float* x     = (const float*)d_in[0];
  const float* decay = (const float*)d_in[1];
  const float* freq  = (const float*)d_in[2];
  float* y = (float*)d_out;

  const int B = 4, T = 8192;  // x: [B, T, D_DIM]

  int C = 256;  // zloc = B*C*D*8 B = 8 MiB
  while (C > 1 && (size_t)B * C * D_DIM * sizeof(float2) > ws_size) C >>= 1;
  int L = T / C;

  float2* zloc = (float2*)d_ws;

  if (C > 1) {
    // chunk C-1's raw carry is never consumed (scan writes its prefix) -> skip it
    dim3 gc(C - 1, B);
    carry_kernel<<<gc, 256, 0, stream>>>(x, decay, freq, zloc, T, L, C);
  }
  scan_kernel<<<dim3(B), 256, 0, stream>>>(decay, freq, zloc, L, C);
  final_kernel<<<dim3(C, B), 256, 0, stream>>>(x, decay, freq, zloc, y, T, L, C);
}

// Round 2
// 287.415 us; speedup vs baseline: 1.2081x; 1.2081x over previous
//
#include <hip/hip_runtime.h>
#include <math.h>

// y[b,t,d] = Re(z[t]),  z[t] = r*z[t-1] + x[t],  r = exp(-|decay[d]|) * e^{i*freq[d]}
//
// 3-kernel blocked scan over t, C chunks of length L = T/C:
//   carry : per chunk, end-state from zero init (reads x once). Chain stepped
//           once per 4 timesteps using r^4 (2 dependent FMAs / 4 t's).
//   scan  : PARALLEL Kogge-Stone prefix scan over the C chunk-carries.
//           Constant per-channel multiplier r^L => first-order linear scan.
//           Grid (D/32, B) = 128 blocks; thread c owns chunk c, 32 channels
//           held in registers, LDS publishes step-k values. 8 steps total.
//           (replaces the 4-block, 255-serial-iteration version: 87 us -> ~5 us)
//   final : per chunk, start from scanned-in state, recompute chunk emitting y.
//           Intermediate outputs y[t..t+2] computed OFF the chain.

#define D_DIM 1024

typedef float floatx4 __attribute__((ext_vector_type(4)));

struct RPow {
  float cr1[4], ci1[4];
  float cr2[4], ci2[4];
  float cr3[4], ci3[4];
  float cr4[4], ci4[4];
};

__device__ __forceinline__ void load_rpow(const float* __restrict__ decay,
                                          const float* __restrict__ freq, int d,
                                          RPow& P) {
  float4 dv = *(const float4*)(decay + d);
  float4 fv = *(const float4*)(freq + d);
  float a[4] = {dv.x, dv.y, dv.z, dv.w};
  float w[4] = {fv.x, fv.y, fv.z, fv.w};
#pragma unroll
  for (int k = 0; k < 4; ++k) {
    float ak = fabsf(a[k]);
    float e = expf(-ak);
    float rr = e * cosf(w[k]);
    float ri = e * sinf(w[k]);
    P.cr1[k] = rr;
    P.ci1[k] = ri;
    float r2r = fmaf(rr, rr, -ri * ri);
    float r2i = 2.f * rr * ri;
    P.cr2[k] = r2r;
    P.ci2[k] = r2i;
    P.cr3[k] = fmaf(r2r, rr, -r2i * ri);
    P.ci3[k] = fmaf(r2r, ri, r2i * rr);
    P.cr4[k] = fmaf(r2r, r2r, -r2i * r2i);
    P.ci4[k] = 2.f * r2r * r2i;
  }
}

__global__ __launch_bounds__(256, 4) void carry_kernel(
    const float* __restrict__ x, const float* __restrict__ decay,
    const float* __restrict__ freq, float2* __restrict__ zloc,
    int T, int L, int C) {
  const int c = blockIdx.x;
  const int b = blockIdx.y;
  const int d = threadIdx.x * 4;  // 4 channels/thread; block covers D=1024

  RPow P;
  load_rpow(decay, freq, d, P);

  const float4* xp =
      (const float4*)(x + ((size_t)b * T + (size_t)c * L) * D_DIM + d);
  const size_t stride = D_DIM / 4;

  float zr[4] = {0.f, 0.f, 0.f, 0.f}, zi[4] = {0.f, 0.f, 0.f, 0.f};
  const int G = L >> 2;  // L always a multiple of 4
#pragma unroll 2
  for (int g = 0; g < G; ++g) {
    const float4* xg = xp + (size_t)g * 4 * stride;
    float4 v0 = xg[0];
    float4 v1 = xg[stride];
    float4 v2 = xg[2 * stride];
    float4 v3 = xg[3 * stride];
    float X0[4] = {v0.x, v0.y, v0.z, v0.w};
    float X1[4] = {v1.x, v1.y, v1.z, v1.w};
    float X2[4] = {v2.x, v2.y, v2.z, v2.w};
    float X3[4] = {v3.x, v3.y, v3.z, v3.w};
#pragma unroll
    for (int k = 0; k < 4; ++k) {
      float sr = fmaf(P.cr3[k], X0[k], fmaf(P.cr2[k], X1[k], fmaf(P.cr1[k], X2[k], X3[k])));
      float si = fmaf(P.ci3[k], X0[k], fmaf(P.ci2[k], X1[k], P.ci1[k] * X2[k]));
      float nr = fmaf(P.cr4[k], zr[k], fmaf(-P.ci4[k], zi[k], sr));
      float ni = fmaf(P.cr4[k], zi[k], fmaf(P.ci4[k], zr[k], si));
      zr[k] = nr;
      zi[k] = ni;
    }
  }

  float4* zp = (float4*)(zloc + ((size_t)b * C + c) * D_DIM + d);
  zp[0] = make_float4(zr[0], zi[0], zr[1], zi[1]);
  zp[1] = make_float4(zr[2], zi[2], zr[3], zi[3]);
}

// Parallel Kogge-Stone exclusive scan over chunk carries, per (b, 32-channel slab).
// zloc[b][c][d] <- sum_{j<c} (r^L)^{c-1-j} * zloc[b][j][d]
// grid = (D_DIM/32, B), 256 threads; thread c owns chunk c (32 channels in regs).
__global__ __launch_bounds__(256) void scan_kernel(
    const float* __restrict__ decay, const float* __restrict__ freq,
    float2* __restrict__ zloc, int L, int C) {
  const int b = blockIdx.y;
  const int dbase = blockIdx.x * 32;
  const int tid = threadIdx.x;

  __shared__ float2 A[32][257];   // [d][c], pad 257 -> 2-way bank aliasing (free)
  __shared__ float2 RLP[8][32];   // (r^L)^(2^k) per channel

  // multiplier table: tid -> (k = tid>>5, d = tid&31); 256 = 8*32 exactly
  {
    int k = tid >> 5, d = tid & 31;
    float a = fabsf(decay[dbase + d]);
    float w = freq[dbase + d];
    float m = (float)L * (float)(1 << k);
    float e = expf(-a * m);
    RLP[k][d] = make_float2(e * cosf(w * m), e * sinf(w * m));
  }

  // cooperative coalesced fill: 32-lane groups load 32 consecutive channels
  {
    int d = tid & 31;
    for (int j = tid >> 5; j < C; j += 8) {
      // zloc[b][C-1] is never written by carry (skipped) and never consumed
      // below; garbage stays confined to I[C-1] which is discarded.
      A[d][j] = zloc[((size_t)b * C + j) * D_DIM + dbase + d];
    }
  }
  __syncthreads();

  const int c = tid;
  const bool own = (c < C);
  float2 I[32];
  if (own) {
#pragma unroll
    for (int d = 0; d < 32; ++d) I[d] = A[d][c];
  }

  for (int k = 0; (1 << k) < C; ++k) {
    const int off = 1 << k;
    if (own && c >= off) {
#pragma unroll
      for (int d = 0; d < 32; ++d) {
        float2 p = A[d][c - off];      // step k-1 values
        float2 m = RLP[k][d];          // broadcast read (free)
        I[d].x = fmaf(m.x, p.x, fmaf(-m.y, p.y, I[d].x));
        I[d].y = fmaf(m.x, p.y, fmaf(m.y, p.x, I[d].y));
      }
    }
    __syncthreads();  // all reads of step k-1 done
    if (own) {
#pragma unroll
      for (int d = 0; d < 32; ++d) A[d][c] = I[d];
    }
    __syncthreads();  // step k values visible
  }

  // writeback exclusive prefix: P[j] = I[j-1], P[0] = 0
  {
    int d = tid & 31;
    for (int j = tid >> 5; j < C; j += 8) {
      float2 v = (j == 0) ? make_float2(0.f, 0.f) : A[d][j - 1];
      zloc[((size_t)b * C + j) * D_DIM + dbase + d] = v;
    }
  }
}

__global__ __launch_bounds__(256, 4) void final_kernel(
    const float* __restrict__ x, const float* __restrict__ decay,
    const float* __restrict__ freq, const float2* __restrict__ zloc,
    float* __restrict__ y, int T, int L, int C) {
  const int c = blockIdx.x;
  const int b = blockIdx.y;
  const int d = threadIdx.x * 4;

  RPow P;
  load_rpow(decay, freq, d, P);

  // incoming state (scanned, exclusive prefix)
  const float2* zl = zloc + ((size_t)b * C + c) * D_DIM + d;
  float4 z0 = *(const float4*)(zl);
  float4 z1 = *(const float4*)(zl + 2);
  float zr[4] = {z0.x, z0.z, z1.x, z1.z};
  float zi[4] = {z0.y, z0.w, z1.y, z1.w};

  const size_t off = ((size_t)b * T + (size_t)c * L) * D_DIM + d;
  const float4* xp = (const float4*)(x + off);
  floatx4* yp = (floatx4*)(y + off);
  const size_t stride = D_DIM / 4;

  const int G = L >> 2;
#pragma unroll 2
  for (int g = 0; g < G; ++g) {
    const float4* xg = xp + (size_t)g * 4 * stride;
    float4 v0 = xg[0];
    float4 v1 = xg[stride];
    float4 v2 = xg[2 * stride];
    float4 v3 = xg[3 * stride];
    float X0[4] = {v0.x, v0.y, v0.z, v0.w};
    float X1[4] = {v1.x, v1.y, v1.z, v1.w};
    float X2[4] = {v2.x, v2.y, v2.z, v2.w};
    float X3[4] = {v3.x, v3.y, v3.z, v3.w};
    float Y0[4], Y1[4], Y2[4], Y3[4];
#pragma unroll
    for (int k = 0; k < 4; ++k) {
      // off-chain real-part outputs for t, t+1, t+2
      Y0[k] = fmaf(P.cr1[k], zr[k], fmaf(-P.ci1[k], zi[k], X0[k]));
      Y1[k] = fmaf(P.cr2[k], zr[k],
                   fmaf(-P.ci2[k], zi[k], fmaf(P.cr1[k], X0[k], X1[k])));
      Y2[k] = fmaf(P.cr3[k], zr[k],
                   fmaf(-P.ci3[k], zi[k],
                        fmaf(P.cr2[k], X0[k], fmaf(P.cr1[k], X1[k], X2[k]))));
      // chain step: z' = r^4 * z + s
      float sr = fmaf(P.cr3[k], X0[k], fmaf(P.cr2[k], X1[k], fmaf(P.cr1[k], X2[k], X3[k])));
      float si = fmaf(P.ci3[k], X0[k], fmaf(P.ci2[k], X1[k], P.ci1[k] * X2[k]));
      float nr = fmaf(P.cr4[k], zr[k], fmaf(-P.ci4[k], zi[k], sr));
      float ni = fmaf(P.cr4[k], zi[k], fmaf(P.ci4[k], zr[k], si));
      zr[k] = nr;
      zi[k] = ni;
      Y3[k] = nr;  // Re(z[t+3])
    }
    // Non-temporal: y never re-read; keep x L3-resident instead.
    floatx4 o0 = {Y0[0], Y0[1], Y0[2], Y0[3]};
    floatx4 o1 = {Y1[0], Y1[1], Y1[2], Y1[3]};
    floatx4 o2 = {Y2[0], Y2[1], Y2[2], Y2[3]};
    floatx4 o3 = {Y3[0], Y3[1], Y3[2], Y3[3]};
    floatx4* yg = yp + (size_t)g * 4 * stride;
    __builtin_nontemporal_store(o0, &yg[0]);
    __builtin_nontemporal_store(o1, &yg[stride]);
    __builtin_nontemporal_store(o2, &yg[2 * stride]);
    __builtin_nontemporal_store(o3, &yg[3 * stride]);
  }
}

extern "C" void kernel_launch(void* const* d_in, const int* in_sizes, int n_in,
                              void* d_out, int out_size, void* d_ws, size_t ws_size,
                              hipStream_t stream) {
  const float* x     = (const float*)d_in[0];
  const float* decay = (const float*)d_in[1];
  const float* freq  = (const float*)d_in[2];
  float* y = (float*)d_out;

  const int B = 4, T = 8192;  // x: [B, T, D_DIM]

  int C = 256;  // zloc = B*C*D*8 B = 8 MiB; scan kernel requires C <= 256
  while (C > 1 && (size_t)B * C * D_DIM * sizeof(float2) > ws_size) C >>= 1;
  int L = T / C;

  float2* zloc = (float2*)d_ws;

  if (C > 1) {
    // chunk C-1's raw carry is never consumed (scan writes its prefix) -> skip it
    dim3 gc(C - 1, B);
    carry_kernel<<<gc, 256, 0, stream>>>(x, decay, freq, zloc, T, L, C);
  }
  scan_kernel<<<dim3(D_DIM / 32, B), 256, 0, stream>>>(decay, freq, zloc, L, C);
  final_kernel<<<dim3(C, B), 256, 0, stream>>>(x, decay, freq, zloc, y, T, L, C);
}